// Round 7
// baseline (344.982 us; speedup 1.0000x reference)
//
#include <hip/hip_runtime.h>

typedef __attribute__((ext_vector_type(8))) short short8;
typedef __attribute__((ext_vector_type(4))) short short4_t;
typedef __attribute__((ext_vector_type(4))) float float4_t;

#define NTOK 4096
#define CDIM 256
#define BPB (NTOK * CDIM)
#define C1 0.0901684400555602f   /* log2(e) / sqrt(256) */

__device__ inline float bf2f(short s) {
    return __uint_as_float(((unsigned)(unsigned short)s) << 16);
}
__device__ inline short f2bf(float f) {
    unsigned u = __float_as_uint(f);
    return (short)((u + 0x7fffu + ((u >> 16) & 1u)) >> 16);
}

// ---------------------------------------------------------------------------
__global__ void sniff_dtype(const unsigned* __restrict__ x, int* __restrict__ flag) {
    __shared__ int cnt;
    if (threadIdx.x == 0) cnt = 0;
    __syncthreads();
    int local = 0;
    for (int i = threadIdx.x; i < 1024; i += 256) {
        unsigned e = (x[i] >> 7) & 0xffu;
        if (e >= 100u && e <= 140u) local++;
    }
    atomicAdd(&cnt, local);
    __syncthreads();
    if (threadIdx.x == 0) flag[0] = (cnt >= 512) ? 1 : 0;
}

// ---------------------------------------------------------------------------
// xpose: x[b][c][n] -> XT[(bl,n)][c] bf16.  PIN: batch from x%8 (XCD pin).
// ---------------------------------------------------------------------------
template <bool PIN>
__global__ __launch_bounds__(256, 2) void xpose(
    const void* __restrict__ xv, int b0, const int* __restrict__ flag,
    short* __restrict__ XT)
{
    int nt, bl;
    if (PIN) {
        bl = (blockIdx.x >> 1) & 3;
        nt = (blockIdx.x >> 3) | ((blockIdx.x & 1) << 3) | (blockIdx.y << 4);
    } else { nt = blockIdx.x; bl = blockIdx.y; }
    const int b = b0 + bl;
    const int n0 = nt * 64;
    const int tid = threadIdx.x;
    __shared__ short xt[64 * 264];

    const size_t xb = (size_t)b * CDIM * NTOK + (size_t)tid * NTOK + n0;
    if (flag[0]) {
        const short* x = (const short*)xv;
        #pragma unroll
        for (int i = 0; i < 8; ++i) {
            short8 v = *(const short8*)(x + xb + i * 8);
            #pragma unroll
            for (int j = 0; j < 8; ++j) xt[(i * 8 + j) * 264 + tid] = v[j];
        }
    } else {
        const float* x = (const float*)xv;
        #pragma unroll
        for (int i = 0; i < 16; ++i) {
            float4 v = *(const float4*)(x + xb + i * 4);
            xt[(i * 4 + 0) * 264 + tid] = f2bf(v.x);
            xt[(i * 4 + 1) * 264 + tid] = f2bf(v.y);
            xt[(i * 4 + 2) * 264 + tid] = f2bf(v.z);
            xt[(i * 4 + 3) * 264 + tid] = f2bf(v.w);
        }
    }
    __syncthreads();

    const int row = tid >> 2, seg = tid & 3;
    const short* src = &xt[row * 264 + seg * 64];
    short* dst = XT + (size_t)(bl * NTOK + n0 + row) * 256 + seg * 64;
    #pragma unroll
    for (int k = 0; k < 8; ++k)
        *(short8*)(dst + k * 8) = *(const short8*)(src + k * 8);
}

// ---------------------------------------------------------------------------
__global__ void wconv(
    const void* Wq, const void* bq, const void* Wk, const void* bk,
    const void* Wv, const void* bv, const int* __restrict__ flag,
    short* __restrict__ Wbf, short* __restrict__ Bbf)
{
    const void* Ws[3] = { Wq, Wk, Wv };
    const void* bs[3] = { bq, bk, bv };
    const int wi = blockIdx.x >> 6, blk = blockIdx.x & 63;
    const int base = blk * 1024 + threadIdx.x * 4;
    if (flag[0]) {
        *(short4_t*)(Wbf + wi * 65536 + base) =
            *(const short4_t*)((const short*)Ws[wi] + base);
        if (blk == 0 && threadIdx.x < 64)
            *(short4_t*)(Bbf + wi * 256 + threadIdx.x * 4) =
                *(const short4_t*)((const short*)bs[wi] + threadIdx.x * 4);
    } else {
        float4 v = *(const float4*)((const float*)Ws[wi] + base);
        short4_t o; o[0]=f2bf(v.x); o[1]=f2bf(v.y); o[2]=f2bf(v.z); o[3]=f2bf(v.w);
        *(short4_t*)(Wbf + wi * 65536 + base) = o;
        if (blk == 0 && threadIdx.x < 64) {
            float4 bv4 = *(const float4*)((const float*)bs[wi] + threadIdx.x * 4);
            short4_t ob; ob[0]=f2bf(bv4.x); ob[1]=f2bf(bv4.y);
            ob[2]=f2bf(bv4.z); ob[3]=f2bf(bv4.w);
            *(short4_t*)(Bbf + wi * 256 + threadIdx.x * 4) = ob;
        }
    }
}

// ---------------------------------------------------------------------------
// qkv3: staged projection (64-dim slab of one W per block), XCD-pinned.
// ---------------------------------------------------------------------------
template <bool PIN>
__global__ __launch_bounds__(256, 3) void qkv3(
    const short* __restrict__ XT, const short* __restrict__ Wbf,
    const short* __restrict__ Bbf,
    short* __restrict__ qbase, short* __restrict__ kbase, short* __restrict__ vtbase)
{
    int nt, bl;
    if (PIN) {
        bl = (blockIdx.x >> 1) & 3;
        nt = (blockIdx.x >> 3) | ((blockIdx.x & 1) << 3) | (blockIdx.z << 4);
    } else { nt = blockIdx.x; bl = blockIdx.z; }
    const int wi = blockIdx.y >> 2, dh = blockIdx.y & 3;
    const int n0 = nt * 64;
    const int tid = threadIdx.x;
    const int w = tid >> 6, lane = tid & 63, l15 = lane & 15, qd = lane >> 4;

    __shared__ short wbuf[64 * 256];

    #pragma unroll
    for (int u = 0; u < 8; ++u) {
        const int fb = u * 256 + tid;
        const int r = fb >> 5, blk = fb & 31;
        short8 v = *(const short8*)(Wbf + wi * 65536 + (dh * 64 + r) * 256 + blk * 8);
        *(short8*)&wbuf[r * 256 + ((blk ^ (r & 31)) * 8)] = v;
    }

    short8 af[8];
    const size_t arow = (size_t)(bl * NTOK + n0 + 16 * w + l15) * 256;
    #pragma unroll
    for (int s = 0; s < 8; ++s)
        af[s] = *(const short8*)(XT + arow + s * 32 + qd * 8);

    __syncthreads();

    short* qdst  = qbase  + (size_t)bl * BPB;
    short* kdst  = kbase  + (size_t)bl * BPB;
    short* vtdst = vtbase + (size_t)bl * BPB;

    #pragma unroll
    for (int dt = 0; dt < 4; ++dt) {
        const int rl = dt * 16 + l15;
        float4_t acc = {0.f, 0.f, 0.f, 0.f};
        #pragma unroll
        for (int s = 0; s < 8; ++s) {
            short8 wb = *(const short8*)&wbuf[rl * 256 + (((s * 4 + qd) ^ (rl & 31)) * 8)];
            acc = __builtin_amdgcn_mfma_f32_16x16x32_bf16(af[s], wb, acc, 0, 0, 0);
        }
        const int d = dh * 64 + dt * 16 + l15;
        const float bias = bf2f(Bbf[wi * 256 + d]);
        if (wi < 2) {
            short* dst = (wi == 0) ? qdst : kdst;
            #pragma unroll
            for (int r = 0; r < 4; ++r) {
                const int n = n0 + 16 * w + 4 * qd + r;
                dst[(size_t)n * 256 + d] = f2bf(acc[r] + bias);
            }
        } else {
            short4_t pk;
            #pragma unroll
            for (int r = 0; r < 4; ++r) pk[r] = f2bf(acc[r] + bias);
            const int n = n0 + 16 * w + 4 * qd;
            *(short4_t*)(vtdst + (size_t)d * NTOK + n) = pk;
        }
    }
}

// ---------------------------------------------------------------------------
// flash6: key-strip S + transposed PV; NO K/V LDS staging.
//   wg = 32 rows x 256 dims, 4 waves.  Per iter (64 keys):
//   S^T:  A = K-strip (wave's 16 keys, direct from L2, wave-private),
//         B = Q (hoisted regs).  -> S once per row (no dim-split duplication)
//   PV^T: A = VT-strip (wave's 64 dims, direct from L2, wave-private),
//         B = P (the ONLY cross-wave data; 4.5 KB LDS round-trip).
//   2 barriers/iter; LDS traffic ~25 KB/wg-iter (was 252 KB in flash5).
// ---------------------------------------------------------------------------
template <bool PIN>
__global__ __launch_bounds__(256, 2) void flash6(
    int b0, const short* __restrict__ qb, const short* __restrict__ kb,
    const short* __restrict__ vtb, const int* __restrict__ flag,
    void* __restrict__ outv)
{
    int qt, bl;
    if (PIN) {
        bl = (blockIdx.x >> 1) & 3;
        qt = ((blockIdx.x >> 3) << 1) | (blockIdx.x & 1);
    } else { qt = blockIdx.x; bl = blockIdx.z; }
    const int b = b0 + bl;
    const int q0 = qt * 32;
    const int tid = threadIdx.x;
    const int w = tid >> 6, lane = tid & 63, l15 = lane & 15, qd = lane >> 4;

    __shared__ short pbuf[32 * 72];     // P[row 32][key 64+pad]
    __shared__ float lbuf[32][4];
    __shared__ float obuf[32 * 260];    // epilogue transpose

    const short* Q  = qb  + (size_t)bl * BPB;
    const short* K  = kb  + (size_t)bl * BPB;
    const short* VT = vtb + (size_t)bl * BPB;

    // hoisted Q B-frags: B[k=c][n=row], rows q0 + nt*16 + l15
    short8 qf[2][8];
    #pragma unroll
    for (int nt = 0; nt < 2; ++nt) {
        const short* qrow = Q + (size_t)(q0 + nt * 16 + l15) * 256;
        #pragma unroll
        for (int s = 0; s < 8; ++s)
            qf[nt][s] = *(const short8*)(qrow + s * 32 + qd * 8);
    }

    // iter-invariant row pointers
    const short* Krow = K + (size_t)(w * 16 + l15) * 256 + qd * 8;   // + k0*256 + s*32
    const short* Vrow[4];
    #pragma unroll
    for (int mt = 0; mt < 4; ++mt)
        Vrow[mt] = VT + (size_t)(w * 64 + mt * 16 + l15) * NTOK + qd * 8; // + k0 + ks*32

    const int pw0 = l15 * 72 + w * 16 + qd * 4;          // P write base (nt adds 16*72)
    const int pr0 = l15 * 72 + qd * 8;                   // P read  base

    float4_t oacc[4][2];
    #pragma unroll
    for (int mt = 0; mt < 4; ++mt)
        #pragma unroll
        for (int nt = 0; nt < 2; ++nt) oacc[mt][nt] = {0.f, 0.f, 0.f, 0.f};
    float lloc[2] = { 0.f, 0.f };

    // preload K A-frags for kt = 0
    short8 kf[8];
    #pragma unroll
    for (int s = 0; s < 8; ++s)
        kf[s] = *(const short8*)(Krow + s * 32);

    for (int kt = 0; kt < 64; ++kt) {
        const int k0 = kt * 64;

        // issue V A-frag loads for this iter (consumed after barrier 1)
        short8 vf[8];
        #pragma unroll
        for (int mt = 0; mt < 4; ++mt)
            #pragma unroll
            for (int ks = 0; ks < 2; ++ks)
                vf[mt * 2 + ks] = *(const short8*)(Vrow[mt] + k0 + ks * 32);

        // ---- S^T = K Q^T for wave's 16 keys x 32 rows ----
        float4_t sacc[2];
        sacc[0] = {0.f, 0.f, 0.f, 0.f};
        sacc[1] = {0.f, 0.f, 0.f, 0.f};
        #pragma unroll
        for (int s = 0; s < 8; ++s) {
            sacc[0] = __builtin_amdgcn_mfma_f32_16x16x32_bf16(kf[s], qf[0][s], sacc[0], 0, 0, 0);
            sacc[1] = __builtin_amdgcn_mfma_f32_16x16x32_bf16(kf[s], qf[1][s], sacc[1], 0, 0, 0);
        }

        // prefetch K A-frags for next iter (covered by exp+PV phase)
        {
            const int kn = ((kt + 1) & 63) * 64;
            #pragma unroll
            for (int s = 0; s < 8; ++s)
                kf[s] = *(const short8*)(Krow + (size_t)kn * 256 + s * 32);
        }

        // ---- P = exp2(C1*S); l accumulate; write cross-wave pbuf ----
        #pragma unroll
        for (int nt = 0; nt < 2; ++nt) {
            #pragma unroll
            for (int r = 0; r < 4; ++r) {
                const float pv = exp2f(sacc[nt][r] * C1);
                lloc[nt] += pv;
                pbuf[nt * (16 * 72) + pw0 + r] = f2bf(pv);
            }
        }
        __syncthreads();   // (1) P visible to all waves

        // ---- O^T += VT * P^T: wave's 64 dims x 32 rows, 64 keys ----
        short8 pb[2][2];
        #pragma unroll
        for (int nt = 0; nt < 2; ++nt)
            #pragma unroll
            for (int ks = 0; ks < 2; ++ks)
                pb[nt][ks] = *(const short8*)&pbuf[nt * (16 * 72) + pr0 + ks * 32];
        #pragma unroll
        for (int mt = 0; mt < 4; ++mt)
            #pragma unroll
            for (int nt = 0; nt < 2; ++nt) {
                oacc[mt][nt] = __builtin_amdgcn_mfma_f32_16x16x32_bf16(
                    vf[mt * 2 + 0], pb[nt][0], oacc[mt][nt], 0, 0, 0);
                oacc[mt][nt] = __builtin_amdgcn_mfma_f32_16x16x32_bf16(
                    vf[mt * 2 + 1], pb[nt][1], oacc[mt][nt], 0, 0, 0);
            }
        __syncthreads();   // (2) pbuf reads done before next iter's writes
    }

    // ---- l: reduce across quads (keys within strip), then across waves ----
    #pragma unroll
    for (int nt = 0; nt < 2; ++nt) {
        float v = lloc[nt];
        v += __shfl_xor(v, 16, 64);
        v += __shfl_xor(v, 32, 64);
        if (qd == 0) lbuf[nt * 16 + l15][w] = v;
    }
    __syncthreads();

    float inv[2];
    #pragma unroll
    for (int nt = 0; nt < 2; ++nt) {
        const int row = nt * 16 + l15;
        inv[nt] = 1.0f / (lbuf[row][0] + lbuf[row][1] + lbuf[row][2] + lbuf[row][3]);
    }

    // ---- transpose O^T -> obuf[row][dim], then coalesced store ----
    #pragma unroll
    for (int mt = 0; mt < 4; ++mt)
        #pragma unroll
        for (int nt = 0; nt < 2; ++nt)
            #pragma unroll
            for (int r = 0; r < 4; ++r)
                obuf[(nt * 16 + l15) * 260 + w * 64 + mt * 16 + qd * 4 + r] =
                    oacc[mt][nt][r] * inv[nt];
    __syncthreads();

    {
        const int row = tid >> 3, seg = tid & 7;
        const float* src = &obuf[row * 260 + seg * 32];
        const size_t o = (size_t)(b * NTOK + q0 + row) * 256 + seg * 32;
        if (flag[0]) {
            short* op = (short*)outv;
            #pragma unroll
            for (int g = 0; g < 4; ++g) {
                short8 pk;
                #pragma unroll
                for (int j = 0; j < 8; ++j) pk[j] = f2bf(src[g * 8 + j]);
                *(short8*)(op + o + g * 8) = pk;
            }
        } else {
            float* op = (float*)outv;
            #pragma unroll
            for (int g = 0; g < 8; ++g)
                *(float4*)(op + o + g * 4) = *(const float4*)(src + g * 4);
        }
    }
}

extern "C" void kernel_launch(void* const* d_in, const int* in_sizes, int n_in,
                              void* d_out, int out_size, void* d_ws, size_t ws_size,
                              hipStream_t stream)
{
    const size_t HDR  = 256;
    const size_t TB   = (size_t)BPB * 2;            // 2 MB per batch per tensor
    const size_t WSTG = (3 * 65536 + 768) * 2;
    const size_t avail = ws_size > HDR ? ws_size - HDR : 0;

    int*   flag  = (int*)d_ws;
    short* kbase = (short*)((char*)d_ws + HDR);

    sniff_dtype<<<1, 256, 0, stream>>>((const unsigned*)d_in[0], flag);

    if (avail >= 16 * TB + WSTG) {
        // primary: K | VT | Q | XT | Wbf | Bbf  (~33 MB)
        short* vtbase = kbase  + 4 * (size_t)BPB;
        short* qbase  = vtbase + 4 * (size_t)BPB;
        short* XT     = qbase  + 4 * (size_t)BPB;
        short* Wbf    = XT     + 4 * (size_t)BPB;
        short* Bbf    = Wbf + 3 * 65536;

        xpose<true><<<dim3(64, 4), 256, 0, stream>>>(d_in[0], 0, flag, XT);
        wconv<<<192, 256, 0, stream>>>(d_in[1], d_in[2], d_in[3], d_in[4],
                                       d_in[5], d_in[6], flag, Wbf, Bbf);
        qkv3<true><<<dim3(64, 12, 4), 256, 0, stream>>>(XT, Wbf, Bbf,
                                                        qbase, kbase, vtbase);
        flash6<true><<<dim3(512, 1, 1), 256, 0, stream>>>(
            0, qbase, kbase, vtbase, flag, d_out);
        return;
    }

    // fallback: batch-chunked, unpinned
    int nb = 4;
    while (nb > 1 && avail < (size_t)nb * 4 * TB + WSTG) nb--;

    short* vtbase = kbase + (size_t)nb * BPB;
    short* xtb    = vtbase + (size_t)nb * BPB;
    short* qbase  = xtb + (size_t)nb * BPB;
    short* Wbf    = qbase + (size_t)nb * BPB;
    short* Bbf    = Wbf + 3 * 65536;

    wconv<<<192, 256, 0, stream>>>(d_in[1], d_in[2], d_in[3], d_in[4],
                                   d_in[5], d_in[6], flag, Wbf, Bbf);
    for (int b0 = 0; b0 < 4; b0 += nb) {
        const int nbc = (4 - b0) < nb ? (4 - b0) : nb;
        xpose<false><<<dim3(64, nbc), 256, 0, stream>>>(d_in[0], b0, flag, xtb);
        qkv3<false><<<dim3(64, 12, nbc), 256, 0, stream>>>(xtb, Wbf, Bbf,
                                                           qbase, kbase, vtbase);
        flash6<false><<<dim3(128, 1, nbc), 256, 0, stream>>>(
            b0, qbase, kbase, vtbase, flag, d_out);
    }
}

// Round 8
// 284.372 us; speedup vs baseline: 1.2131x; 1.2131x over previous
//
#include <hip/hip_runtime.h>

typedef __attribute__((ext_vector_type(8))) short short8;
typedef __attribute__((ext_vector_type(4))) short short4_t;
typedef __attribute__((ext_vector_type(4))) float float4_t;
typedef __attribute__((ext_vector_type(16))) float float16_t;

#define NTOK 4096
#define CDIM 256
#define BPB (NTOK * CDIM)
#define C1 0.0901684400555602f   /* log2(e) / sqrt(256) */

__device__ inline float bf2f(short s) {
    return __uint_as_float(((unsigned)(unsigned short)s) << 16);
}
__device__ inline short f2bf(float f) {
    unsigned u = __float_as_uint(f);
    return (short)((u + 0x7fffu + ((u >> 16) & 1u)) >> 16);
}

// ---------------------------------------------------------------------------
__global__ void sniff_dtype(const unsigned* __restrict__ x, int* __restrict__ flag) {
    __shared__ int cnt;
    if (threadIdx.x == 0) cnt = 0;
    __syncthreads();
    int local = 0;
    for (int i = threadIdx.x; i < 1024; i += 256) {
        unsigned e = (x[i] >> 7) & 0xffu;
        if (e >= 100u && e <= 140u) local++;
    }
    atomicAdd(&cnt, local);
    __syncthreads();
    if (threadIdx.x == 0) flag[0] = (cnt >= 512) ? 1 : 0;
}

// ---------------------------------------------------------------------------
// xpose: x[b][c][n] -> XT[(bl,n)][c] bf16.  PIN: batch from x%8 (XCD pin).
// ---------------------------------------------------------------------------
template <bool PIN>
__global__ __launch_bounds__(256, 2) void xpose(
    const void* __restrict__ xv, int b0, const int* __restrict__ flag,
    short* __restrict__ XT)
{
    int nt, bl;
    if (PIN) {
        bl = (blockIdx.x >> 1) & 3;
        nt = (blockIdx.x >> 3) | ((blockIdx.x & 1) << 3) | (blockIdx.y << 4);
    } else { nt = blockIdx.x; bl = blockIdx.y; }
    const int b = b0 + bl;
    const int n0 = nt * 64;
    const int tid = threadIdx.x;
    __shared__ short xt[64 * 264];

    const size_t xb = (size_t)b * CDIM * NTOK + (size_t)tid * NTOK + n0;
    if (flag[0]) {
        const short* x = (const short*)xv;
        #pragma unroll
        for (int i = 0; i < 8; ++i) {
            short8 v = *(const short8*)(x + xb + i * 8);
            #pragma unroll
            for (int j = 0; j < 8; ++j) xt[(i * 8 + j) * 264 + tid] = v[j];
        }
    } else {
        const float* x = (const float*)xv;
        #pragma unroll
        for (int i = 0; i < 16; ++i) {
            float4 v = *(const float4*)(x + xb + i * 4);
            xt[(i * 4 + 0) * 264 + tid] = f2bf(v.x);
            xt[(i * 4 + 1) * 264 + tid] = f2bf(v.y);
            xt[(i * 4 + 2) * 264 + tid] = f2bf(v.z);
            xt[(i * 4 + 3) * 264 + tid] = f2bf(v.w);
        }
    }
    __syncthreads();

    const int row = tid >> 2, seg = tid & 3;
    const short* src = &xt[row * 264 + seg * 64];
    short* dst = XT + (size_t)(bl * NTOK + n0 + row) * 256 + seg * 64;
    #pragma unroll
    for (int k = 0; k < 8; ++k)
        *(short8*)(dst + k * 8) = *(const short8*)(src + k * 8);
}

// ---------------------------------------------------------------------------
__global__ void wconv(
    const void* Wq, const void* bq, const void* Wk, const void* bk,
    const void* Wv, const void* bv, const int* __restrict__ flag,
    short* __restrict__ Wbf, short* __restrict__ Bbf)
{
    const void* Ws[3] = { Wq, Wk, Wv };
    const void* bs[3] = { bq, bk, bv };
    const int wi = blockIdx.x >> 6, blk = blockIdx.x & 63;
    const int base = blk * 1024 + threadIdx.x * 4;
    if (flag[0]) {
        *(short4_t*)(Wbf + wi * 65536 + base) =
            *(const short4_t*)((const short*)Ws[wi] + base);
        if (blk == 0 && threadIdx.x < 64)
            *(short4_t*)(Bbf + wi * 256 + threadIdx.x * 4) =
                *(const short4_t*)((const short*)bs[wi] + threadIdx.x * 4);
    } else {
        float4 v = *(const float4*)((const float*)Ws[wi] + base);
        short4_t o; o[0]=f2bf(v.x); o[1]=f2bf(v.y); o[2]=f2bf(v.z); o[3]=f2bf(v.w);
        *(short4_t*)(Wbf + wi * 65536 + base) = o;
        if (blk == 0 && threadIdx.x < 64) {
            float4 bv4 = *(const float4*)((const float*)bs[wi] + threadIdx.x * 4);
            short4_t ob; ob[0]=f2bf(bv4.x); ob[1]=f2bf(bv4.y);
            ob[2]=f2bf(bv4.z); ob[3]=f2bf(bv4.w);
            *(short4_t*)(Bbf + wi * 256 + threadIdx.x * 4) = ob;
        }
    }
}

// ---------------------------------------------------------------------------
// qkv3b: projection; one W per block, 4 dim-slabs streamed through LDS
// (XT A-frags hoisted once -> XT global re-read x3 instead of x12).
// ---------------------------------------------------------------------------
template <bool PIN>
__global__ __launch_bounds__(256, 3) void qkv3b(
    const short* __restrict__ XT, const short* __restrict__ Wbf,
    const short* __restrict__ Bbf,
    short* __restrict__ qbase, short* __restrict__ kbase, short* __restrict__ vtbase)
{
    int nt, bl;
    if (PIN) {
        bl = (blockIdx.x >> 1) & 3;
        nt = ((blockIdx.x >> 3) << 1) | (blockIdx.x & 1);
    } else { nt = blockIdx.x; bl = blockIdx.z; }
    const int wi = blockIdx.y;
    const int n0 = nt * 64;
    const int tid = threadIdx.x;
    const int w = tid >> 6, lane = tid & 63, l15 = lane & 15, qd = lane >> 4;

    __shared__ short wbuf[64 * 256];

    short8 af[8];
    const size_t arow = (size_t)(bl * NTOK + n0 + 16 * w + l15) * 256;
    #pragma unroll
    for (int s = 0; s < 8; ++s)
        af[s] = *(const short8*)(XT + arow + s * 32 + qd * 8);

    short* qdst  = qbase  + (size_t)bl * BPB;
    short* kdst  = kbase  + (size_t)bl * BPB;
    short* vtdst = vtbase + (size_t)bl * BPB;

    for (int dh = 0; dh < 4; ++dh) {
        #pragma unroll
        for (int u = 0; u < 8; ++u) {
            const int fb = u * 256 + tid;
            const int r = fb >> 5, blk = fb & 31;
            short8 v = *(const short8*)(Wbf + wi * 65536 + (dh * 64 + r) * 256 + blk * 8);
            *(short8*)&wbuf[r * 256 + ((blk ^ (r & 31)) * 8)] = v;
        }
        __syncthreads();

        #pragma unroll
        for (int dt = 0; dt < 4; ++dt) {
            const int rl = dt * 16 + l15;
            float4_t acc = {0.f, 0.f, 0.f, 0.f};
            #pragma unroll
            for (int s = 0; s < 8; ++s) {
                short8 wb = *(const short8*)&wbuf[rl * 256 + (((s * 4 + qd) ^ (rl & 31)) * 8)];
                acc = __builtin_amdgcn_mfma_f32_16x16x32_bf16(af[s], wb, acc, 0, 0, 0);
            }
            const int d = dh * 64 + dt * 16 + l15;
            const float bias = bf2f(Bbf[wi * 256 + d]);
            if (wi < 2) {
                short* dst = (wi == 0) ? qdst : kdst;
                #pragma unroll
                for (int r = 0; r < 4; ++r) {
                    const int n = n0 + 16 * w + 4 * qd + r;
                    dst[(size_t)n * 256 + d] = f2bf(acc[r] + bias);
                }
            } else {
                short4_t pk;
                #pragma unroll
                for (int r = 0; r < 4; ++r) pk[r] = f2bf(acc[r] + bias);
                const int n = n0 + 16 * w + 4 * qd;
                *(short4_t*)(vtdst + (size_t)d * NTOK + n) = pk;
            }
        }
        __syncthreads();
    }
}

// ---------------------------------------------------------------------------
// flash8: 32x32x16 MFMA, transposed-S layout, coalesced reg-prefetch staging.
// wg = 64 qrows x 256 dims x all 4096 keys.  Per iter (64 keys):
//   S^T tile per wave (wi=key-tile, wh=qrow-tile): A = K (LDS), B = Q (regs).
//   C-layout of S^T gives 4-contiguous keys -> P written as b64 packs,
//   read back as b128 A-frags for PV (A = P, B = V from LDS).
// All LDS XOR-swizzled on 16B granules (<=2-way everywhere).
// 3 barriers/iter; global K/V prefetched to regs across the whole compute.
// ---------------------------------------------------------------------------
template <bool PIN>
__global__ __launch_bounds__(256, 2) void flash8(
    int b0, const short* __restrict__ qb, const short* __restrict__ kb,
    const short* __restrict__ vtb, const int* __restrict__ flag,
    void* __restrict__ outv)
{
    int qt, bl;
    if (PIN) {
        bl = (blockIdx.x >> 1) & 3;
        qt = ((blockIdx.x >> 3) << 1) | (blockIdx.x & 1);
    } else { qt = blockIdx.x; bl = blockIdx.z; }
    const int b = b0 + bl;
    const int q0 = qt * 64;
    const int tid = threadIdx.x;
    const int w = tid >> 6, lane = tid & 63, l31 = lane & 31, h = lane >> 5;
    const int wi = w & 1, wh = w >> 1;

    __shared__ char smem[81920];
    short* kbuf = (short*)smem;             // 64 rows x 512B, granule ^ (r&31)
    short* vbuf = (short*)(smem + 32768);   // 256 rows x 128B, granule ^ (r&7)
    short* pbuf = (short*)(smem + 65536);   // 64 rows x 128B, granule ^ (r&7)

    const short* Q  = qb  + (size_t)bl * BPB;
    const short* K  = kb  + (size_t)bl * BPB;
    const short* VT = vtb + (size_t)bl * BPB;

    // Q B-frags (S^T): B[k=c][n=qrow]; lane n=l31 -> row q0+32wh+l31, k=8h+j
    short8 qf[16];
    {
        const short* qrow = Q + (size_t)(q0 + 32 * wh + l31) * 256 + h * 8;
        #pragma unroll
        for (int s = 0; s < 16; ++s)
            qf[s] = *(const short8*)(qrow + s * 16);
    }

    float16_t oacc[4];
    #pragma unroll
    for (int dt = 0; dt < 4; ++dt)
        #pragma unroll
        for (int r = 0; r < 16; ++r) oacc[dt][r] = 0.f;
    float lloc = 0.f;

    // staging ownership
    const int krw = tid >> 5, kgc = tid & 31;   // K: r = u*8+krw, g = kgc
    const int vrw = tid >> 3, vgc = tid & 7;    // V: r = u*32+vrw, g = vgc

    short8 kpre[8], vpre[8];
    #pragma unroll
    for (int u = 0; u < 8; ++u) {
        const int r = u * 8 + krw;
        kpre[u] = *(const short8*)(K + (size_t)r * 256 + kgc * 8);
    }
    #pragma unroll
    for (int u = 0; u < 8; ++u) {
        const int r = u * 32 + vrw;
        vpre[u] = *(const short8*)(VT + (size_t)r * NTOK + vgc * 8);
    }

    const int kread_row = 32 * wi + l31;         // S: A = K rows (keys)
    const int prow = 32 * wh + l31;              // P rows (qrows)

    #pragma unroll 1
    for (int kt = 0; kt < 64; ++kt) {
        __syncthreads();   // (a) prev PV done with all LDS buffers

        #pragma unroll
        for (int u = 0; u < 8; ++u) {
            const int r = u * 8 + krw;
            *(short8*)&kbuf[r * 256 + ((kgc ^ (r & 31)) * 8)] = kpre[u];
        }
        #pragma unroll
        for (int u = 0; u < 8; ++u) {
            const int r = u * 32 + vrw;
            *(short8*)&vbuf[r * 64 + ((vgc ^ (r & 7)) * 8)] = vpre[u];
        }
        __syncthreads();   // (b) staging visible

        if (kt < 63) {     // prefetch next tile (in flight through compute)
            const int k1 = (kt + 1) * 64;
            #pragma unroll
            for (int u = 0; u < 8; ++u) {
                const int r = u * 8 + krw;
                kpre[u] = *(const short8*)(K + (size_t)(k1 + r) * 256 + kgc * 8);
            }
            #pragma unroll
            for (int u = 0; u < 8; ++u) {
                const int r = u * 32 + vrw;
                vpre[u] = *(const short8*)(VT + (size_t)r * NTOK + k1 + vgc * 8);
            }
        }

        // ---- S^T tile: keys 32wi x qrows 32wh ----
        float16_t sacc;
        #pragma unroll
        for (int r = 0; r < 16; ++r) sacc[r] = 0.f;
        #pragma unroll
        for (int s = 0; s < 16; ++s) {
            short8 kf = *(const short8*)
                &kbuf[kread_row * 256 + (((2 * s + h) ^ (kread_row & 31)) * 8)];
            sacc = __builtin_amdgcn_mfma_f32_32x32x16_bf16(kf, qf[s], sacc, 0, 0, 0);
        }

        // ---- P = exp2(C1*S); l accumulate; b64 packs to pbuf ----
        #pragma unroll
        for (int g2 = 0; g2 < 4; ++g2) {
            short4_t pk;
            #pragma unroll
            for (int r = 0; r < 4; ++r) {
                const float pv = exp2f(sacc[4 * g2 + r] * C1);
                lloc += pv;
                pk[r] = f2bf(pv);
            }
            const int gk = 4 * wi + g2;
            *(short4_t*)&pbuf[prow * 64 + ((gk ^ (prow & 7)) * 8) + h * 4] = pk;
        }
        __syncthreads();   // (c) P complete

        // ---- O += P V: qrows 32wh x dims 128wi..+128 ----
        short8 pa[4];
        #pragma unroll
        for (int s2 = 0; s2 < 4; ++s2)
            pa[s2] = *(const short8*)
                &pbuf[prow * 64 + (((2 * s2 + h) ^ (prow & 7)) * 8)];
        #pragma unroll
        for (int dt = 0; dt < 4; ++dt) {
            const int vr = 128 * wi + 32 * dt + l31;
            #pragma unroll
            for (int s2 = 0; s2 < 4; ++s2) {
                short8 vf = *(const short8*)
                    &vbuf[vr * 64 + (((2 * s2 + h) ^ (vr & 7)) * 8)];
                oacc[dt] = __builtin_amdgcn_mfma_f32_32x32x16_bf16(pa[s2], vf, oacc[dt], 0, 0, 0);
            }
        }
    }

    // ---- epilogue ----
    __syncthreads();
    float* obuf = (float*)smem;                   // 64 x 260 fp32 (66560 B)
    float* lbuf = (float*)(smem + 66560);         // 64 x 2 fp32

    {
        float v = lloc + __shfl_xor(lloc, 32, 64);
        if (h == 0) lbuf[(32 * wh + l31) * 2 + wi] = v;
    }
    #pragma unroll
    for (int dt = 0; dt < 4; ++dt) {
        const int dim = 128 * wi + 32 * dt + l31;
        #pragma unroll
        for (int r = 0; r < 16; ++r) {
            const int qrow = 32 * wh + (r & 3) + 8 * (r >> 2) + 4 * h;
            obuf[qrow * 260 + dim] = oacc[dt][r];
        }
    }
    __syncthreads();

    {
        const int row = tid >> 2, q4 = (tid & 3) * 64;
        const float inv = 1.0f / (lbuf[2 * row] + lbuf[2 * row + 1]);
        const float* src = obuf + row * 260 + q4;
        const size_t o = (size_t)(b * NTOK + q0 + row) * 256 + q4;
        if (flag[0]) {
            short* op = (short*)outv;
            #pragma unroll
            for (int g = 0; g < 4; ++g) {
                float4 a = *(const float4*)(src + g * 8);
                float4 c4 = *(const float4*)(src + g * 8 + 4);
                short8 pk;
                pk[0]=f2bf(a.x*inv);  pk[1]=f2bf(a.y*inv);
                pk[2]=f2bf(a.z*inv);  pk[3]=f2bf(a.w*inv);
                pk[4]=f2bf(c4.x*inv); pk[5]=f2bf(c4.y*inv);
                pk[6]=f2bf(c4.z*inv); pk[7]=f2bf(c4.w*inv);
                *(short8*)(op + o + g * 8) = pk;
            }
        } else {
            float* op = (float*)outv;
            #pragma unroll
            for (int g = 0; g < 16; ++g) {
                float4 a = *(const float4*)(src + g * 4);
                a.x *= inv; a.y *= inv; a.z *= inv; a.w *= inv;
                *(float4*)(op + o + g * 4) = a;
            }
        }
    }
}

extern "C" void kernel_launch(void* const* d_in, const int* in_sizes, int n_in,
                              void* d_out, int out_size, void* d_ws, size_t ws_size,
                              hipStream_t stream)
{
    const size_t HDR  = 256;
    const size_t TB   = (size_t)BPB * 2;            // 2 MB per batch per tensor
    const size_t WSTG = (3 * 65536 + 768) * 2;
    const size_t avail = ws_size > HDR ? ws_size - HDR : 0;

    int*   flag  = (int*)d_ws;
    short* kbase = (short*)((char*)d_ws + HDR);

    sniff_dtype<<<1, 256, 0, stream>>>((const unsigned*)d_in[0], flag);

    if (avail >= 16 * TB + WSTG) {
        // primary: K | VT | Q | XT | Wbf | Bbf  (~33 MB)
        short* vtbase = kbase  + 4 * (size_t)BPB;
        short* qbase  = vtbase + 4 * (size_t)BPB;
        short* XT     = qbase  + 4 * (size_t)BPB;
        short* Wbf    = XT     + 4 * (size_t)BPB;
        short* Bbf    = Wbf + 3 * 65536;

        xpose<true><<<dim3(64, 4), 256, 0, stream>>>(d_in[0], 0, flag, XT);
        wconv<<<192, 256, 0, stream>>>(d_in[1], d_in[2], d_in[3], d_in[4],
                                       d_in[5], d_in[6], flag, Wbf, Bbf);
        qkv3b<true><<<dim3(256, 3, 1), 256, 0, stream>>>(XT, Wbf, Bbf,
                                                         qbase, kbase, vtbase);
        flash8<true><<<dim3(256, 1, 1), 256, 0, stream>>>(
            0, qbase, kbase, vtbase, flag, d_out);
        return;
    }

    // fallback: batch-chunked, unpinned
    int nb = 4;
    while (nb > 1 && avail < (size_t)nb * 4 * TB + WSTG) nb--;

    short* vtbase = kbase + (size_t)nb * BPB;
    short* xtb    = vtbase + (size_t)nb * BPB;
    short* qbase  = xtb + (size_t)nb * BPB;
    short* Wbf    = qbase + (size_t)nb * BPB;
    short* Bbf    = Wbf + 3 * 65536;

    wconv<<<192, 256, 0, stream>>>(d_in[1], d_in[2], d_in[3], d_in[4],
                                   d_in[5], d_in[6], flag, Wbf, Bbf);
    for (int b0 = 0; b0 < 4; b0 += nb) {
        const int nbc = (4 - b0) < nb ? (4 - b0) : nb;
        xpose<false><<<dim3(64, nbc), 256, 0, stream>>>(d_in[0], b0, flag, xtb);
        qkv3b<false><<<dim3(64, 3, nbc), 256, 0, stream>>>(xtb, Wbf, Bbf,
                                                           qbase, kbase, vtbase);
        flash8<false><<<dim3(64, 1, nbc), 256, 0, stream>>>(
            b0, qbase, kbase, vtbase, flag, d_out);
    }
}

// Round 9
// 260.761 us; speedup vs baseline: 1.3230x; 1.0905x over previous
//
#include <hip/hip_runtime.h>

typedef __attribute__((ext_vector_type(8))) short short8;
typedef __attribute__((ext_vector_type(4))) short short4_t;
typedef __attribute__((ext_vector_type(4))) float float4_t;
typedef __attribute__((ext_vector_type(16))) float float16_t;

#define NTOK 4096
#define CDIM 256
#define BPB (NTOK * CDIM)
#define C1 0.0901684400555602f   /* log2(e) / sqrt(256) */

__device__ inline float bf2f(short s) {
    return __uint_as_float(((unsigned)(unsigned short)s) << 16);
}
__device__ inline short f2bf(float f) {
    unsigned u = __float_as_uint(f);
    return (short)((u + 0x7fffu + ((u >> 16) & 1u)) >> 16);
}

// ---------------------------------------------------------------------------
__global__ void sniff_dtype(const unsigned* __restrict__ x, int* __restrict__ flag) {
    __shared__ int cnt;
    if (threadIdx.x == 0) cnt = 0;
    __syncthreads();
    int local = 0;
    for (int i = threadIdx.x; i < 1024; i += 256) {
        unsigned e = (x[i] >> 7) & 0xffu;
        if (e >= 100u && e <= 140u) local++;
    }
    atomicAdd(&cnt, local);
    __syncthreads();
    if (threadIdx.x == 0) flag[0] = (cnt >= 512) ? 1 : 0;
}

// ---------------------------------------------------------------------------
// qkv4: fused transpose + projection. One block = 64 tokens x all 3 W.
// X tile transposed in LDS; W streamed through LDS in 12 reg-prefetched
// slabs.  Q,K stored [n][d]; V stored transposed VT[d][n].
// ---------------------------------------------------------------------------
template <bool PIN>
__global__ __launch_bounds__(256, 1) void qkv4(
    const void* __restrict__ xv,
    const void* __restrict__ Wq, const void* __restrict__ bq,
    const void* __restrict__ Wk, const void* __restrict__ bk,
    const void* __restrict__ Wv, const void* __restrict__ bv,
    const int* __restrict__ flag, int b0,
    short* __restrict__ qbase, short* __restrict__ kbase,
    short* __restrict__ vtbase)
{
    int nt, bl;
    if (PIN) {
        bl = (blockIdx.x >> 1) & 3;
        nt = ((blockIdx.x >> 3) << 1) | (blockIdx.x & 1);
    } else { nt = blockIdx.x; bl = blockIdx.z; }
    const int b = b0 + bl;
    const int n0 = nt * 64;
    const int tid = threadIdx.x;
    const int w = tid >> 6, lane = tid & 63, l15 = lane & 15, qd = lane >> 4;
    const int isbf = flag[0];

    __shared__ short xt[64 * 264];     // 33792 B
    __shared__ short wbuf[64 * 256];   // 32768 B

    // ---- stage X tile transposed: thread owns channel c = tid ----
    {
        const size_t xb = (size_t)b * CDIM * NTOK + (size_t)tid * NTOK + n0;
        if (isbf) {
            const short* x = (const short*)xv;
            #pragma unroll
            for (int i = 0; i < 8; ++i) {
                short8 v = *(const short8*)(x + xb + i * 8);
                #pragma unroll
                for (int j = 0; j < 8; ++j) xt[(i * 8 + j) * 264 + tid] = v[j];
            }
        } else {
            const float* x = (const float*)xv;
            #pragma unroll
            for (int i = 0; i < 16; ++i) {
                float4 v = *(const float4*)(x + xb + i * 4);
                xt[(i * 4 + 0) * 264 + tid] = f2bf(v.x);
                xt[(i * 4 + 1) * 264 + tid] = f2bf(v.y);
                xt[(i * 4 + 2) * 264 + tid] = f2bf(v.z);
                xt[(i * 4 + 3) * 264 + tid] = f2bf(v.w);
            }
        }
    }
    __syncthreads();

    short8 af[8];
    #pragma unroll
    for (int s = 0; s < 8; ++s)
        af[s] = *(const short8*)&xt[(16 * w + l15) * 264 + s * 32 + qd * 8];

    const void* Ws[3] = { Wq, Wk, Wv };
    const void* bs[3] = { bq, bk, bv };
    short* qdst  = qbase  + (size_t)bl * BPB;
    short* kdst  = kbase  + (size_t)bl * BPB;
    short* vtdst = vtbase + (size_t)bl * BPB;

    // W slab prefetch registers (one dtype path active)
    float4 wf[16];
    short8 wb8[8];

    #define LOADSLAB(WI, DH)                                                  \
        if (isbf) {                                                           \
            const short* Wp = (const short*)Ws[WI];                           \
            _Pragma("unroll")                                                 \
            for (int u = 0; u < 8; ++u) {                                     \
                const int fb = u * 256 + tid, r = fb >> 5, blk = fb & 31;     \
                wb8[u] = *(const short8*)(Wp + ((DH) * 64 + r) * 256 + blk * 8); \
            }                                                                 \
        } else {                                                              \
            const float* Wp = (const float*)Ws[WI];                           \
            _Pragma("unroll")                                                 \
            for (int u = 0; u < 8; ++u) {                                     \
                const int fb = u * 256 + tid, r = fb >> 5, blk = fb & 31;     \
                wf[2*u]   = *(const float4*)(Wp + ((DH)*64 + r)*256 + blk*8); \
                wf[2*u+1] = *(const float4*)(Wp + ((DH)*64 + r)*256 + blk*8 + 4); \
            }                                                                 \
        }

    LOADSLAB(0, 0);

    for (int sl = 0; sl < 12; ++sl) {
        const int wi = sl >> 2, dh = sl & 3;
        __syncthreads();   // prev compute done reading wbuf

        #pragma unroll
        for (int u = 0; u < 8; ++u) {
            const int fb = u * 256 + tid, r = fb >> 5, blk = fb & 31;
            short8 v;
            if (isbf) v = wb8[u];
            else {
                float4 a = wf[2*u], c4 = wf[2*u+1];
                v[0]=f2bf(a.x);  v[1]=f2bf(a.y);  v[2]=f2bf(a.z);  v[3]=f2bf(a.w);
                v[4]=f2bf(c4.x); v[5]=f2bf(c4.y); v[6]=f2bf(c4.z); v[7]=f2bf(c4.w);
            }
            *(short8*)&wbuf[r * 256 + ((blk ^ (r & 31)) * 8)] = v;
        }
        __syncthreads();

        if (sl + 1 < 12) { LOADSLAB((sl + 1) >> 2, (sl + 1) & 3); }

        #pragma unroll
        for (int dt = 0; dt < 4; ++dt) {
            const int rl = dt * 16 + l15;
            float4_t acc = {0.f, 0.f, 0.f, 0.f};
            #pragma unroll
            for (int s = 0; s < 8; ++s) {
                short8 wb = *(const short8*)&wbuf[rl * 256 + (((s * 4 + qd) ^ (rl & 31)) * 8)];
                acc = __builtin_amdgcn_mfma_f32_16x16x32_bf16(af[s], wb, acc, 0, 0, 0);
            }
            const int d = dh * 64 + dt * 16 + l15;
            const float bias = isbf ? bf2f(((const short*)bs[wi])[d])
                                    : ((const float*)bs[wi])[d];
            if (wi < 2) {
                short* dst = (wi == 0) ? qdst : kdst;
                #pragma unroll
                for (int r = 0; r < 4; ++r) {
                    const int n = n0 + 16 * w + 4 * qd + r;
                    dst[(size_t)n * 256 + d] = f2bf(acc[r] + bias);
                }
            } else {
                short4_t pk;
                #pragma unroll
                for (int r = 0; r < 4; ++r) pk[r] = f2bf(acc[r] + bias);
                const int n = n0 + 16 * w + 4 * qd;
                *(short4_t*)(vtdst + (size_t)d * NTOK + n) = pk;
            }
        }
    }
    #undef LOADSLAB
}

// ---------------------------------------------------------------------------
// flash9: 32x32x16 MFMA, transposed-S layout, FULL double-buffer pipeline:
// ONE barrier per iter.  At iter kt (between barriers):
//   stage K(kt+1)->kbuf[alt], V(kt)->vbuf[cur]   (from prefetch regs)
//   prefetch K(kt+2), V(kt+1) -> regs            (global, in flight)
//   S(kt) from kbuf[cur] (2 indep MFMA chains), exp, P(kt)->pbuf[cur]
//   PV(kt-1) from pbuf[prev] + vbuf[prev]
// LDS 144 KB (1 wg/CU by design); staging/S/PV share the inter-barrier
// window so the LDS pipe never drains.
// ---------------------------------------------------------------------------
template <bool PIN>
__global__ __launch_bounds__(256, 1) void flash9(
    int b0, const short* __restrict__ qb, const short* __restrict__ kb,
    const short* __restrict__ vtb, const int* __restrict__ flag,
    void* __restrict__ outv)
{
    int qt, bl;
    if (PIN) {
        bl = (blockIdx.x >> 1) & 3;
        qt = ((blockIdx.x >> 3) << 1) | (blockIdx.x & 1);
    } else { qt = blockIdx.x; bl = blockIdx.z; }
    const int b = b0 + bl;
    const int q0 = qt * 64;
    const int tid = threadIdx.x;
    const int w = tid >> 6, lane = tid & 63, l31 = lane & 31, h = lane >> 5;
    const int wi = w & 1, wh = w >> 1;

    __shared__ char smem[147456];
    short* kbufA = (short*)smem;               // 2 x 32 KB
    short* vbufA = (short*)(smem + 65536);     // 2 x 32 KB
    short* pbufA = (short*)(smem + 131072);    // 2 x 8 KB

    const short* Q  = qb  + (size_t)bl * BPB;
    const short* K  = kb  + (size_t)bl * BPB;
    const short* VT = vtb + (size_t)bl * BPB;

    // Q B-frags: B[k=c][n=qrow], lane n=l31 -> row q0+32wh+l31, k = 8h+j
    short8 qf[16];
    {
        const short* qrow = Q + (size_t)(q0 + 32 * wh + l31) * 256 + h * 8;
        #pragma unroll
        for (int s = 0; s < 16; ++s)
            qf[s] = *(const short8*)(qrow + s * 16);
    }

    float16_t oacc[4];
    #pragma unroll
    for (int dt = 0; dt < 4; ++dt)
        #pragma unroll
        for (int r = 0; r < 16; ++r) oacc[dt][r] = 0.f;
    float lloc = 0.f;

    const int krw = tid >> 5, kgc = tid & 31;
    const int vrw = tid >> 3, vgc = tid & 7;
    const int kread_row = 32 * wi + l31;
    const int prow = 32 * wh + l31;

    short8 kregs[8], vregs[8];
    // kregs = K(0); stage kbuf[0]; then prefetch K(1), V(0)
    #pragma unroll
    for (int u = 0; u < 8; ++u) {
        const int r = u * 8 + krw;
        kregs[u] = *(const short8*)(K + (size_t)r * 256 + kgc * 8);
    }
    #pragma unroll
    for (int u = 0; u < 8; ++u) {
        const int r = u * 8 + krw;
        *(short8*)&kbufA[r * 256 + ((kgc ^ (r & 31)) * 8)] = kregs[u];
    }
    #pragma unroll
    for (int u = 0; u < 8; ++u) {
        const int r = u * 8 + krw;
        kregs[u] = *(const short8*)(K + (size_t)(64 + r) * 256 + kgc * 8);
    }
    #pragma unroll
    for (int u = 0; u < 8; ++u) {
        const int r = u * 32 + vrw;
        vregs[u] = *(const short8*)(VT + (size_t)r * NTOK + vgc * 8);
    }
    __syncthreads();

    #pragma unroll 1
    for (int kt = 0; kt < 64; ++kt) {
        short* kcur  = kbufA + (kt & 1) * 16384;
        short* knext = kbufA + ((kt + 1) & 1) * 16384;
        short* vcur  = vbufA + (kt & 1) * 16384;
        short* vprev = vbufA + ((kt + 1) & 1) * 16384;   // (kt-1)&1
        short* pcur  = pbufA + (kt & 1) * 4096;
        short* pprev = pbufA + ((kt + 1) & 1) * 4096;

        // ---- stage from prefetch regs ----
        if (kt < 63) {
            #pragma unroll
            for (int u = 0; u < 8; ++u) {
                const int r = u * 8 + krw;
                *(short8*)&knext[r * 256 + ((kgc ^ (r & 31)) * 8)] = kregs[u];
            }
        }
        #pragma unroll
        for (int u = 0; u < 8; ++u) {
            const int r = u * 32 + vrw;
            *(short8*)&vcur[r * 64 + ((vgc ^ (r & 7)) * 8)] = vregs[u];
        }

        // ---- global prefetch (in flight through the rest of the iter) ----
        if (kt < 62) {
            const int k2 = (kt + 2) * 64;
            #pragma unroll
            for (int u = 0; u < 8; ++u) {
                const int r = u * 8 + krw;
                kregs[u] = *(const short8*)(K + (size_t)(k2 + r) * 256 + kgc * 8);
            }
        }
        if (kt < 63) {
            const int k1 = (kt + 1) * 64;
            #pragma unroll
            for (int u = 0; u < 8; ++u) {
                const int r = u * 32 + vrw;
                vregs[u] = *(const short8*)(VT + (size_t)r * NTOK + k1 + vgc * 8);
            }
        }

        // ---- S(kt): keys 32wi x qrows 32wh, 2 independent chains ----
        float16_t se, so;
        #pragma unroll
        for (int r = 0; r < 16; ++r) { se[r] = 0.f; so[r] = 0.f; }
        #pragma unroll
        for (int j = 0; j < 8; ++j) {
            short8 kfa = *(const short8*)
                &kcur[kread_row * 256 + (((4 * j + h) ^ (kread_row & 31)) * 8)];
            se = __builtin_amdgcn_mfma_f32_32x32x16_bf16(kfa, qf[2 * j], se, 0, 0, 0);
            short8 kfb = *(const short8*)
                &kcur[kread_row * 256 + (((4 * j + 2 + h) ^ (kread_row & 31)) * 8)];
            so = __builtin_amdgcn_mfma_f32_32x32x16_bf16(kfb, qf[2 * j + 1], so, 0, 0, 0);
        }

        // ---- P = exp2(C1*S); l accumulate; b64 packs to pcur ----
        #pragma unroll
        for (int g2 = 0; g2 < 4; ++g2) {
            short4_t pk;
            #pragma unroll
            for (int r = 0; r < 4; ++r) {
                const float pv = exp2f((se[4 * g2 + r] + so[4 * g2 + r]) * C1);
                lloc += pv;
                pk[r] = f2bf(pv);
            }
            const int gk = 4 * wi + g2;
            *(short4_t*)&pcur[prow * 64 + ((gk ^ (prow & 7)) * 8) + h * 4] = pk;
        }

        // ---- PV(kt-1): qrows 32wh x dims 128wi..+128 ----
        if (kt > 0) {
            short8 pa[4];
            #pragma unroll
            for (int s2 = 0; s2 < 4; ++s2)
                pa[s2] = *(const short8*)
                    &pprev[prow * 64 + (((2 * s2 + h) ^ (prow & 7)) * 8)];
            #pragma unroll
            for (int dt = 0; dt < 4; ++dt) {
                const int vr = 128 * wi + 32 * dt + l31;
                #pragma unroll
                for (int s2 = 0; s2 < 4; ++s2) {
                    short8 vf = *(const short8*)
                        &vprev[vr * 64 + (((2 * s2 + h) ^ (vr & 7)) * 8)];
                    oacc[dt] = __builtin_amdgcn_mfma_f32_32x32x16_bf16(pa[s2], vf, oacc[dt], 0, 0, 0);
                }
            }
        }

        __syncthreads();   // the ONE barrier
    }

    // ---- drain: PV(63) from pbuf[1], vbuf[1] ----
    {
        short* pprev = pbufA + 4096;
        short* vprev = vbufA + 16384;
        short8 pa[4];
        #pragma unroll
        for (int s2 = 0; s2 < 4; ++s2)
            pa[s2] = *(const short8*)
                &pprev[prow * 64 + (((2 * s2 + h) ^ (prow & 7)) * 8)];
        #pragma unroll
        for (int dt = 0; dt < 4; ++dt) {
            const int vr = 128 * wi + 32 * dt + l31;
            #pragma unroll
            for (int s2 = 0; s2 < 4; ++s2) {
                short8 vf = *(const short8*)
                    &vprev[vr * 64 + (((2 * s2 + h) ^ (vr & 7)) * 8)];
                oacc[dt] = __builtin_amdgcn_mfma_f32_32x32x16_bf16(pa[s2], vf, oacc[dt], 0, 0, 0);
            }
        }
    }

    // ---- epilogue (obuf overlays kbuf region — dead now) ----
    float* obuf = (float*)smem;                   // 64 x 260 fp32
    float* lbuf = (float*)(smem + 66560);         // 64 x 2 fp32

    {
        float v = lloc + __shfl_xor(lloc, 32, 64);
        if (h == 0) lbuf[(32 * wh + l31) * 2 + wi] = v;
    }
    #pragma unroll
    for (int dt = 0; dt < 4; ++dt) {
        const int dim = 128 * wi + 32 * dt + l31;
        #pragma unroll
        for (int r = 0; r < 16; ++r) {
            const int qrow = 32 * wh + (r & 3) + 8 * (r >> 2) + 4 * h;
            obuf[qrow * 260 + dim] = oacc[dt][r];
        }
    }
    __syncthreads();

    {
        const int row = tid >> 2, q4 = (tid & 3) * 64;
        const float inv = 1.0f / (lbuf[2 * row] + lbuf[2 * row + 1]);
        const float* src = obuf + row * 260 + q4;
        const size_t o = (size_t)(b * NTOK + q0 + row) * 256 + q4;
        if (flag[0]) {
            short* op = (short*)outv;
            #pragma unroll
            for (int g = 0; g < 4; ++g) {
                float4 a = *(const float4*)(src + g * 8);
                float4 c4 = *(const float4*)(src + g * 8 + 4);
                short8 pk;
                pk[0]=f2bf(a.x*inv);  pk[1]=f2bf(a.y*inv);
                pk[2]=f2bf(a.z*inv);  pk[3]=f2bf(a.w*inv);
                pk[4]=f2bf(c4.x*inv); pk[5]=f2bf(c4.y*inv);
                pk[6]=f2bf(c4.z*inv); pk[7]=f2bf(c4.w*inv);
                *(short8*)(op + o + g * 8) = pk;
            }
        } else {
            float* op = (float*)outv;
            #pragma unroll
            for (int g = 0; g < 16; ++g) {
                float4 a = *(const float4*)(src + g * 4);
                a.x *= inv; a.y *= inv; a.z *= inv; a.w *= inv;
                *(float4*)(op + o + g * 4) = a;
            }
        }
    }
}

extern "C" void kernel_launch(void* const* d_in, const int* in_sizes, int n_in,
                              void* d_out, int out_size, void* d_ws, size_t ws_size,
                              hipStream_t stream)
{
    const size_t HDR = 256;
    const size_t TB  = (size_t)BPB * 2;            // 2 MB per batch per tensor
    const size_t avail = ws_size > HDR ? ws_size - HDR : 0;

    int*   flag  = (int*)d_ws;
    short* kbase = (short*)((char*)d_ws + HDR);

    sniff_dtype<<<1, 256, 0, stream>>>((const unsigned*)d_in[0], flag);

    if (avail >= 12 * TB) {
        // primary: K | VT | Q (24 MB)
        short* vtbase = kbase  + 4 * (size_t)BPB;
        short* qbase  = vtbase + 4 * (size_t)BPB;
        qkv4<true><<<dim3(256, 1, 1), 256, 0, stream>>>(
            d_in[0], d_in[1], d_in[2], d_in[3], d_in[4], d_in[5], d_in[6],
            flag, 0, qbase, kbase, vtbase);
        flash9<true><<<dim3(256, 1, 1), 256, 0, stream>>>(
            0, qbase, kbase, vtbase, flag, d_out);
        return;
    }

    // fallback: batch-chunked (K|VT|Q per chunk = 6 MB/batch)
    int nb = 4;
    while (nb > 1 && avail < (size_t)nb * 3 * TB) nb--;
    short* vtbase = kbase + (size_t)nb * BPB;
    short* qbase  = vtbase + (size_t)nb * BPB;

    for (int b0 = 0; b0 < 4; b0 += nb) {
        const int nbc = (4 - b0) < nb ? (4 - b0) : nb;
        qkv4<false><<<dim3(64, 1, nbc), 256, 0, stream>>>(
            d_in[0], d_in[1], d_in[2], d_in[3], d_in[4], d_in[5], d_in[6],
            flag, b0, qbase, kbase, vtbase);
        flash9<false><<<dim3(64, 1, nbc), 256, 0, stream>>>(
            b0, qbase, kbase, vtbase, flag, d_out);
    }
}